// Round 1
// baseline (254.889 us; speedup 1.0000x reference)
//
#include <hip/hip_runtime.h>

#define EXT 40
#define SQ (EXT*EXT)

__device__ __forceinline__ unsigned um_min(unsigned a, unsigned b){ return a < b ? a : b; }
__device__ __forceinline__ unsigned um_max(unsigned a, unsigned b){ return a > b ? a : b; }

// arr sorted descending; keeps the 14 smallest keys seen. Branchless bubble insert.
__device__ __forceinline__ void insert14(unsigned (&arr)[14], unsigned key){
  arr[0] = um_min(arr[0], key);
  #pragma unroll
  for (int s = 0; s < 13; ++s){
    unsigned a = arr[s], b = arr[s+1];
    arr[s]   = um_max(a, b);
    arr[s+1] = um_min(a, b);
  }
}

// Build reflect-padded rescaled image Xp[3][288][288]. Means cancel (see analysis) so
// we skip mean removal entirely.
__global__ void k_prep(const float* __restrict__ noisy, float* __restrict__ Xp){
  int idx = blockIdx.x * 256 + threadIdx.x;
  if (idx >= 288*288) return;
  int P = idx / 288, Q = idx - P*288;
  int sy = P - 16; sy = sy < 0 ? -sy : sy; sy = sy > 255 ? 510 - sy : sy;
  int sx = Q - 16; sx = sx < 0 ? -sx : sx; sx = sx > 255 ? 510 - sx : sx;
  const float inv = 1.0f / 127.5f;
  int src = sy*256 + sx;
  #pragma unroll
  for (int c = 0; c < 3; ++c)
    Xp[c*82944 + idx] = noisy[c*65536 + src] * inv - 1.0f;
}

template<int R>
__device__ __forceinline__ void ssd_step(const float* rowbase, int dx, unsigned obase,
                                         float (&cp)[5][5], float (&win)[5][5],
                                         unsigned (&arr)[14]){
  constexpr int nc = (R + 4) % 5;
  #pragma unroll
  for (int u = 0; u < 5; ++u) win[u][nc] = rowbase[u*EXT + dx + 4];
  float s = 0.f;
  #pragma unroll
  for (int u = 0; u < 5; ++u){
    #pragma unroll
    for (int v = 0; v < 5; ++v){
      float d = cp[u][v] - win[u][(R + v) % 5];
      s = fmaf(d, d, s);
    }
  }
  insert14(arr, (__float_as_uint(s) & 0xFFFFFC00u) | (obase + (unsigned)dx));
}

// One 8x8 pixel tile per 256-thread block. 4 waves split the 29 dy rows of the
// search window; per-lane rolling-window SSD + sorted-14 packed-key selection;
// LDS merge; softmax aggregation; LDS overlap-add fold; global atomic fold.
__global__ __launch_bounds__(256, 4) void k_search(const float* __restrict__ Xp,
      const float* __restrict__ sigma, const float* __restrict__ wgray,
      float* __restrict__ accG){
  __shared__ float sXp[3*SQ];        // 19200 B  color tile rows [bi..bi+39]
  __shared__ float sG[SQ];           //  6400 B  grayscale tile
  __shared__ unsigned sCand[3*64*14];// 10752 B  per-wave candidates / merged
  __shared__ float sWsum[64];        //   256 B  softmax denominators
  __shared__ float sFold[12*12*3];   //  1728 B  overlap-add tile

  const int tid = threadIdx.x;
  const int w = tid >> 6, l = tid & 63;
  const int ly = l >> 3, lx = l & 7;
  const int bi = blockIdx.y * 8, bj = blockIdx.x * 8;

  // stage color tile (coalesced)
  for (int t = tid; t < 3*SQ; t += 256){
    int c = t / SQ; int r2 = t - c*SQ; int rr = r2 / EXT; int cc = r2 - rr*EXT;
    sXp[t] = Xp[c*82944 + (bi+rr)*288 + (bj+cc)];
  }
  if (tid < 64) sWsum[tid] = 0.f;
  for (int t = tid; t < 432; t += 256) sFold[t] = 0.f;
  __syncthreads();
  const float w0 = wgray[0], w1 = wgray[1], w2 = wgray[2];
  for (int t = tid; t < SQ; t += 256)
    sG[t] = w0*sXp[t] + w1*sXp[SQ+t] + w2*sXp[2*SQ+t];
  __syncthreads();

  // center 5x5 grayscale patch -> registers
  float cp[5][5];
  #pragma unroll
  for (int u = 0; u < 5; ++u)
    #pragma unroll
    for (int v = 0; v < 5; ++v)
      cp[u][v] = sG[(14 + ly + u)*EXT + 14 + lx + v];

  unsigned arr[14];
  #pragma unroll
  for (int k = 0; k < 14; ++k) arr[k] = 0xFFFFFFFFu;

  const int dy0 = (w == 0) ? 0 : 1 + 7*w;        // 0, 8, 15, 22
  const int dy1 = dy0 + ((w == 0) ? 8 : 7);

  for (int dy = dy0; dy < dy1; ++dy){
    const float* rowbase = &sG[(dy + ly)*EXT + lx];
    float win[5][5];
    #pragma unroll
    for (int u = 0; u < 5; ++u)
      #pragma unroll
      for (int v = 0; v < 4; ++v)
        win[u][v] = rowbase[u*EXT + v];
    const unsigned obase = (unsigned)(dy * 29);

    for (int b = 0; b < 5; ++b){
      int dxb = b * 5;
      ssd_step<0>(rowbase, dxb+0, obase, cp, win, arr);
      ssd_step<1>(rowbase, dxb+1, obase, cp, win, arr);
      ssd_step<2>(rowbase, dxb+2, obase, cp, win, arr);
      ssd_step<3>(rowbase, dxb+3, obase, cp, win, arr);
      ssd_step<4>(rowbase, dxb+4, obase, cp, win, arr);
    }
    ssd_step<0>(rowbase, 25, obase, cp, win, arr);
    ssd_step<1>(rowbase, 26, obase, cp, win, arr);
    ssd_step<2>(rowbase, 27, obase, cp, win, arr);
    ssd_step<3>(rowbase, 28, obase, cp, win, arr);
  }

  // merge 4 waves' top-14 -> global top-14 (union insert is exact)
  if (w){
    #pragma unroll
    for (int k = 0; k < 14; ++k) sCand[((w-1)*64 + l)*14 + k] = arr[k];
  }
  __syncthreads();
  if (!w){
    for (int q = 0; q < 3; ++q)
      #pragma unroll
      for (int k = 0; k < 14; ++k)
        insert14(arr, sCand[(q*64 + l)*14 + k]);
    #pragma unroll
    for (int k = 0; k < 14; ++k) sCand[l*14 + k] = arr[k];
  }
  __syncthreads();

  // ---- phase 2: softmax weights + weighted patch aggregation ----
  float sg = sigma[0] * (1.0f / 127.5f);
  const float invT = 1.0f / (sg*sg*25.0f + 1e-8f);
  const float dmin = __uint_as_float(sCand[l*14 + 13] & 0xFFFFFC00u);

  float wgt[4]; int ndy[4], ndx[4];
  const int nk = (w < 2) ? 4 : 3;          // neighbor counts per wave: 4,4,3,3
  float Sp = 0.f;
  #pragma unroll
  for (int m = 0; m < 4; ++m){
    if (m < nk){
      unsigned kk = sCand[l*14 + (w + 4*m)];
      float d = __uint_as_float(kk & 0xFFFFFC00u);
      int o = (int)(kk & 0x3FFu);
      wgt[m] = expf(-(d - dmin) * invT);
      ndy[m] = o / 29; ndx[m] = o - ndy[m]*29;
      Sp += wgt[m];
    }
  }
  atomicAdd(&sWsum[l], Sp);
  __syncthreads();
  const float invS = 1.0f / sWsum[l];
  #pragma unroll
  for (int m = 0; m < 4; ++m) if (m < nk) wgt[m] *= invS;

  #pragma unroll
  for (int c = 0; c < 3; ++c){
    float acc[5][5];
    #pragma unroll
    for (int u = 0; u < 5; ++u)
      #pragma unroll
      for (int v = 0; v < 5; ++v) acc[u][v] = 0.f;
    #pragma unroll
    for (int m = 0; m < 4; ++m){
      if (m < nk){
        const float* pb = &sXp[c*SQ + (ly + ndy[m])*EXT + lx + ndx[m]];
        float g = wgt[m];
        #pragma unroll
        for (int u = 0; u < 5; ++u)
          #pragma unroll
          for (int v = 0; v < 5; ++v)
            acc[u][v] = fmaf(g, pb[u*EXT + v], acc[u][v]);
      }
    }
    // overlap-add into 12x12 tile; per (u,v) round lanes hit distinct cells
    #pragma unroll
    for (int u = 0; u < 5; ++u)
      #pragma unroll
      for (int v = 0; v < 5; ++v)
        atomicAdd(&sFold[((ly+u)*12 + (lx+v))*3 + c], acc[u][v]);
  }
  __syncthreads();
  for (int t = tid; t < 432; t += 256){
    int c = t % 3; int rc = t / 3; int rr = rc / 12; int cc = rc - rr*12;
    atomicAdd(&accG[c*67600 + (bi+rr)*260 + (bj+cc)], sFold[t]);
  }
}

// deno = acc/cnt; out = 127.5*deno + 127.5  (means cancel)
__global__ void k_finish(const float* __restrict__ accG, float* __restrict__ out){
  int idx = blockIdx.x * 256 + threadIdx.x;
  if (idx >= 3*65536) return;
  int c = idx >> 16; int rem = idx & 65535; int y = rem >> 8; int x = rem & 255;
  int cy = min(4, y + 2) - max(0, y - 253) + 1;
  int cx = min(4, x + 2) - max(0, x - 253) + 1;
  float v = accG[c*67600 + (y+2)*260 + (x+2)] / (float)(cy * cx);
  out[idx] = 127.5f * v + 127.5f;
}

extern "C" void kernel_launch(void* const* d_in, const int* in_sizes, int n_in,
                              void* d_out, int out_size, void* d_ws, size_t ws_size,
                              hipStream_t stream) {
  const float* noisy = (const float*)d_in[0];
  const float* sigma = (const float*)d_in[1];
  const float* wgray = (const float*)d_in[2];
  float* out  = (float*)d_out;
  float* Xp   = (float*)d_ws;                  // 3*288*288 floats
  float* accG = Xp + 3*288*288;                // 3*260*260 floats

  hipMemsetAsync(accG, 0, 3*260*260*sizeof(float), stream);
  k_prep<<<dim3(324), dim3(256), 0, stream>>>(noisy, Xp);
  k_search<<<dim3(32, 32), dim3(256), 0, stream>>>(Xp, sigma, wgray, accG);
  k_finish<<<dim3(768), dim3(256), 0, stream>>>(accG, out);
}

// Round 2
// 232.468 us; speedup vs baseline: 1.0964x; 1.0964x over previous
//
#include <hip/hip_runtime.h>

#define EXT 40
#define SQ (EXT*EXT)

__device__ __forceinline__ unsigned um_min(unsigned a, unsigned b){ return a < b ? a : b; }
__device__ __forceinline__ unsigned um_max(unsigned a, unsigned b){ return a > b ? a : b; }
__device__ __forceinline__ unsigned med3u(unsigned a, unsigned b, unsigned c){
  unsigned d;
  asm("v_med3_u32 %0, %1, %2, %3" : "=v"(d) : "v"(a), "v"(b), "v"(c));
  return d;
}

// arr sorted descending (arr[0] = largest of the kept 14 smallest).
// Insert key, drop the max of the 15. med3 network: 15 ops, dep depth 2.
__device__ __forceinline__ void insert14(unsigned (&a)[14], unsigned key){
  unsigned kp  = um_min(key, a[0]);
  unsigned n0  = um_max(a[1], kp);
  unsigned n13 = um_min(a[13], kp);
  unsigned nn[12];
  #pragma unroll
  for (int i = 1; i <= 12; ++i) nn[i-1] = med3u(a[i], a[i+1], kp);
  a[0] = n0;
  #pragma unroll
  for (int i = 1; i <= 12; ++i) a[i] = nn[i-1];
  a[13] = n13;
}

// Reflect-padded rescaled image Xp[3][288][288] (means cancel -> skipped),
// plus zero-init of the global fold accumulator (replaces hipMemsetAsync).
__global__ void k_prep(const float* __restrict__ noisy, float* __restrict__ Xp,
                       float* __restrict__ accG){
  int idx = blockIdx.x * 256 + threadIdx.x;
  if (idx < 3*260*260) accG[idx] = 0.f;
  if (idx >= 288*288) return;
  int P = idx / 288, Q = idx - P*288;
  int sy = P - 16; sy = sy < 0 ? -sy : sy; sy = sy > 255 ? 510 - sy : sy;
  int sx = Q - 16; sx = sx < 0 ? -sx : sx; sx = sx > 255 ? 510 - sx : sx;
  const float inv = 1.0f / 127.5f;
  int src = sy*256 + sx;
  #pragma unroll
  for (int c = 0; c < 3; ++c)
    Xp[c*82944 + idx] = noisy[c*65536 + src] * inv - 1.0f;
}

// One dx step, fully unrolled (DX compile-time -> ds_read offsets are immediates).
// SSD by expansion: dist = cpsq + winsq - 2*cross, winsq kept as rolling column-ssq sum.
template<int DX>
__device__ __forceinline__ void ssd_step(const float* rowbase, unsigned obase,
                                         const float (&cp)[5][5], float cpsq,
                                         float (&win)[5][5], float (&ring)[5],
                                         float& winsq, unsigned (&arr)[14]){
  constexpr int nc = (DX + 4) % 5;
  #pragma unroll
  for (int u = 0; u < 5; ++u) win[u][nc] = rowbase[u*EXT + DX + 4];
  float nssq = win[0][nc]*win[0][nc];
  #pragma unroll
  for (int u = 1; u < 5; ++u) nssq = fmaf(win[u][nc], win[u][nc], nssq);
  winsq += (nssq - ring[nc]);
  ring[nc] = nssq;
  float c0=0.f, c1=0.f, c2=0.f, c3=0.f, c4=0.f;
  #pragma unroll
  for (int v = 0; v < 5; ++v){
    constexpr int dummy = 0; (void)dummy;
    c0 = fmaf(cp[0][v], win[0][(DX + v) % 5], c0);
    c1 = fmaf(cp[1][v], win[1][(DX + v) % 5], c1);
    c2 = fmaf(cp[2][v], win[2][(DX + v) % 5], c2);
    c3 = fmaf(cp[3][v], win[3][(DX + v) % 5], c3);
    c4 = fmaf(cp[4][v], win[4][(DX + v) % 5], c4);
  }
  float cross = ((c0 + c1) + (c2 + c3)) + c4;
  float dist = fmaf(cross, -2.0f, cpsq + winsq);
  dist = fmaxf(dist, 0.0f);   // cancellation guard: self-offset must stay non-negative
  insert14(arr, (__float_as_uint(dist) & 0xFFFFFC00u) | (obase + (unsigned)DX));
}

template<int DX>
__device__ __forceinline__ void row_steps(const float* rowbase, unsigned obase,
                                          const float (&cp)[5][5], float cpsq,
                                          float (&win)[5][5], float (&ring)[5],
                                          float& winsq, unsigned (&arr)[14]){
  if constexpr (DX < 29){
    ssd_step<DX>(rowbase, obase, cp, cpsq, win, ring, winsq, arr);
    row_steps<DX+1>(rowbase, obase, cp, cpsq, win, ring, winsq, arr);
  }
}

// One 8x8 pixel tile per 256-thread block; 4 waves split the 29 dy rows.
__global__ __launch_bounds__(256, 4) void k_search(const float* __restrict__ Xp,
      const float* __restrict__ sigma, const float* __restrict__ wgray,
      float* __restrict__ accG){
  __shared__ float sXp[3*SQ];        // 19200 B color tile
  __shared__ float sG[SQ];           //  6400 B grayscale tile
  __shared__ unsigned sCand[3*64*14];// 10752 B per-wave candidates
  __shared__ float sWsum[64];
  __shared__ float sFold[12*12*3];

  const int tid = threadIdx.x;
  const int w = tid >> 6, l = tid & 63;
  const int ly = l >> 3, lx = l & 7;
  const int bi = blockIdx.y * 8, bj = blockIdx.x * 8;

  for (int t = tid; t < 3*SQ; t += 256){
    int c = t / SQ; int r2 = t - c*SQ; int rr = r2 / EXT; int cc = r2 - rr*EXT;
    sXp[t] = Xp[c*82944 + (bi+rr)*288 + (bj+cc)];
  }
  if (tid < 64) sWsum[tid] = 0.f;
  for (int t = tid; t < 432; t += 256) sFold[t] = 0.f;
  __syncthreads();
  const float w0 = wgray[0], w1 = wgray[1], w2 = wgray[2];
  for (int t = tid; t < SQ; t += 256)
    sG[t] = w0*sXp[t] + w1*sXp[SQ+t] + w2*sXp[2*SQ+t];
  __syncthreads();

  // center 5x5 grayscale patch + its squared norm (column-wise sum order)
  float cp[5][5];
  #pragma unroll
  for (int u = 0; u < 5; ++u)
    #pragma unroll
    for (int v = 0; v < 5; ++v)
      cp[u][v] = sG[(14 + ly + u)*EXT + 14 + lx + v];
  float cpsq = 0.f;
  #pragma unroll
  for (int v = 0; v < 5; ++v){
    float cs = cp[0][v]*cp[0][v];
    #pragma unroll
    for (int u = 1; u < 5; ++u) cs = fmaf(cp[u][v], cp[u][v], cs);
    cpsq += cs;
  }

  unsigned arr[14];
  #pragma unroll
  for (int k = 0; k < 14; ++k) arr[k] = 0xFFFFFFFFu;

  const int dy0 = (w == 0) ? 0 : 1 + 7*w;        // 0, 8, 15, 22
  const int dy1 = dy0 + ((w == 0) ? 8 : 7);

  #pragma unroll 1
  for (int dy = dy0; dy < dy1; ++dy){
    const float* rowbase = &sG[(dy + ly)*EXT + lx];
    float win[5][5], ring[5], winsq;
    #pragma unroll
    for (int v = 0; v < 4; ++v){
      #pragma unroll
      for (int u = 0; u < 5; ++u) win[u][v] = rowbase[u*EXT + v];
      float cs = win[0][v]*win[0][v];
      #pragma unroll
      for (int u = 1; u < 5; ++u) cs = fmaf(win[u][v], win[u][v], cs);
      ring[v] = cs;
    }
    ring[4] = 0.f;
    winsq = (ring[0] + ring[1]) + (ring[2] + ring[3]);
    row_steps<0>(rowbase, (unsigned)(dy*29), cp, cpsq, win, ring, winsq, arr);
  }

  // merge 4 waves' top-14 -> global top-14
  if (w){
    #pragma unroll
    for (int k = 0; k < 14; ++k) sCand[((w-1)*64 + l)*14 + k] = arr[k];
  }
  __syncthreads();
  if (!w){
    for (int q = 0; q < 3; ++q)
      #pragma unroll
      for (int k = 0; k < 14; ++k)
        insert14(arr, sCand[(q*64 + l)*14 + k]);
    #pragma unroll
    for (int k = 0; k < 14; ++k) sCand[l*14 + k] = arr[k];
  }
  __syncthreads();

  // ---- phase 2: softmax weights + weighted patch aggregation ----
  float sg = sigma[0] * (1.0f / 127.5f);
  const float invT = 1.0f / (sg*sg*25.0f + 1e-8f);
  const float dmin = __uint_as_float(sCand[l*14 + 13] & 0xFFFFFC00u);

  float wgt[4]; int ndy[4], ndx[4];
  const int nk = (w < 2) ? 4 : 3;
  float Sp = 0.f;
  #pragma unroll
  for (int m = 0; m < 4; ++m){
    if (m < nk){
      unsigned kk = sCand[l*14 + (w + 4*m)];
      float d = __uint_as_float(kk & 0xFFFFFC00u);
      int o = (int)(kk & 0x3FFu);
      wgt[m] = expf(-(d - dmin) * invT);
      ndy[m] = o / 29; ndx[m] = o - ndy[m]*29;
      Sp += wgt[m];
    }
  }
  atomicAdd(&sWsum[l], Sp);
  __syncthreads();
  const float invS = 1.0f / sWsum[l];
  #pragma unroll
  for (int m = 0; m < 4; ++m) if (m < nk) wgt[m] *= invS;

  #pragma unroll
  for (int c = 0; c < 3; ++c){
    float acc[5][5];
    #pragma unroll
    for (int u = 0; u < 5; ++u)
      #pragma unroll
      for (int v = 0; v < 5; ++v) acc[u][v] = 0.f;
    #pragma unroll
    for (int m = 0; m < 4; ++m){
      if (m < nk){
        const float* pb = &sXp[c*SQ + (ly + ndy[m])*EXT + lx + ndx[m]];
        float g = wgt[m];
        #pragma unroll
        for (int u = 0; u < 5; ++u)
          #pragma unroll
          for (int v = 0; v < 5; ++v)
            acc[u][v] = fmaf(g, pb[u*EXT + v], acc[u][v]);
      }
    }
    #pragma unroll
    for (int u = 0; u < 5; ++u)
      #pragma unroll
      for (int v = 0; v < 5; ++v)
        atomicAdd(&sFold[((ly+u)*12 + (lx+v))*3 + c], acc[u][v]);
  }
  __syncthreads();
  for (int t = tid; t < 432; t += 256){
    int c = t % 3; int rc = t / 3; int rr = rc / 12; int cc = rc - rr*12;
    atomicAdd(&accG[c*67600 + (bi+rr)*260 + (bj+cc)], sFold[t]);
  }
}

__global__ void k_finish(const float* __restrict__ accG, float* __restrict__ out){
  int idx = blockIdx.x * 256 + threadIdx.x;
  if (idx >= 3*65536) return;
  int c = idx >> 16; int rem = idx & 65535; int y = rem >> 8; int x = rem & 255;
  int cy = min(4, y + 2) - max(0, y - 253) + 1;
  int cx = min(4, x + 2) - max(0, x - 253) + 1;
  float v = accG[c*67600 + (y+2)*260 + (x+2)] / (float)(cy * cx);
  out[idx] = 127.5f * v + 127.5f;
}

extern "C" void kernel_launch(void* const* d_in, const int* in_sizes, int n_in,
                              void* d_out, int out_size, void* d_ws, size_t ws_size,
                              hipStream_t stream) {
  const float* noisy = (const float*)d_in[0];
  const float* sigma = (const float*)d_in[1];
  const float* wgray = (const float*)d_in[2];
  float* out  = (float*)d_out;
  float* Xp   = (float*)d_ws;                  // 3*288*288 floats
  float* accG = Xp + 3*288*288;                // 3*260*260 floats

  k_prep<<<dim3(793), dim3(256), 0, stream>>>(noisy, Xp, accG);
  k_search<<<dim3(32, 32), dim3(256), 0, stream>>>(Xp, sigma, wgray, accG);
  k_finish<<<dim3(768), dim3(256), 0, stream>>>(accG, out);
}